// Round 1
// baseline (3168.902 us; speedup 1.0000x reference)
//
#include <hip/hip_runtime.h>
#include <math.h>

// ---------------------------------------------------------------------------
// MultiViewFeatureTransformer — round 0 baseline, pure fp32 vector-ALU.
// Design notes:
//  * All roll/split/window reshapes are folded into GEMM output index math.
//  * Shift-window mask computed on the fly (matches _make_mask regions), incl.
//    the reference's cross-attn quirk: mask col = key_index % 256 where
//    key_index = spatial*M + view.
//  * Workspace map (floats):
//      Qw   [384*256*128]                      (also reused as MSG2 later)
//      Kw   [384*512*128]   (self uses first half-stride layout bn*256+t)
//      Vw   [384*512*128]
//      SRCb [98304*128]
//    partial[4][98304][128] aliases Kw..Vw (dead after cross-attn).
//    X (attention output, token layout) aliases d_out.
//    Peak ws = 301,989,888 bytes.
// ---------------------------------------------------------------------------

typedef float f4 __attribute__((ext_vector_type(4)));
typedef float f2 __attribute__((ext_vector_type(2)));

constexpr int Dm   = 128;
constexpr int IH   = 128, IW = 128;
constexpr int Bq   = 6;
constexpr int Mv   = 2;
constexpr int WSZ  = 256;
constexpr int TOK  = IH * IW;            // 16384
constexpr int ROWS = Bq * TOK;           // 98304
constexpr int KVROWS = Bq * Mv * TOK;    // 196608
constexpr int BN   = Bq * 64;            // 384
constexpr float SCALE = 0.08838834764831845f;  // 1/sqrt(128)

// token row -> windowed row (roll by (-8,-8), 8x8 grid of 16x16 windows)
__device__ __forceinline__ int dest_row_self(int r) {
  int b = r >> 14;
  int p = r & 16383;
  int y = p >> 7, x = p & 127;
  int Y = (y + 120) & 127, X = (x + 120) & 127;
  int bn = (b << 6) + ((Y >> 4) << 3) + (X >> 4);
  int t  = ((Y & 15) << 4) + (X & 15);
  return bn * WSZ + t;
}

// kv row (b, view, spatial) -> cross windowed row: key index = t*Mv + view
__device__ __forceinline__ int dest_row_cross(int r) {
  int b  = r >> 15;
  int vi = (r >> 14) & 1;
  int p  = r & 16383;
  int y = p >> 7, x = p & 127;
  int Y = (y + 120) & 127, X = (x + 120) & 127;
  int bn = (b << 6) + ((Y >> 4) << 3) + (X >> 4);
  int t  = ((Y & 15) << 4) + (X & 15);
  return bn * (WSZ * Mv) + t * Mv + vi;
}

// ---------------------------------------------------------------------------
// Projection GEMM: out[dest(r)][c] = sum_k A[r][k] * B[k][c],  K = 128.
// 64 rows x 128 cols per block, 256 threads, 8x4 micro-tile.
// MODE 0: self qkv (3 mats, self-windowed dest)
// MODE 1: q2       (1 mat,  self-windowed dest)
// MODE 2: k2/v2    (2 mats, cross-windowed dest)
// ---------------------------------------------------------------------------
template<int NMAT, int MODE>
__global__ __launch_bounds__(256, 2)
void proj_kernel(const float* __restrict__ A,
                 const float* __restrict__ B0, const float* __restrict__ B1,
                 const float* __restrict__ B2,
                 float* __restrict__ O0, float* __restrict__ O1,
                 float* __restrict__ O2)
{
  __shared__ float At[128][68];   // A tile transposed [k][row]
  __shared__ float Bs[64][132];   // B k-chunk [k][c]
  const int tid  = threadIdx.x;
  const int row0 = blockIdx.x * 64;

  { // stage A transposed (coalesced global, scalar LDS writes)
    const int tr = tid >> 2;
    const int tc = (tid & 3) * 4;
    const float* Ar = A + (size_t)(row0 + tr) * Dm;
    #pragma unroll
    for (int i = 0; i < 8; ++i) {
      int c = tc + i * 16;
      f4 a = *(const f4*)(Ar + c);
      At[c + 0][tr] = a[0];
      At[c + 1][tr] = a[1];
      At[c + 2][tr] = a[2];
      At[c + 3][tr] = a[3];
    }
  }

  const int tcol = tid & 31;   // cols tcol*4 .. +3
  const int trow = tid >> 5;   // rows trow*8 .. +7

  int drow[8];
  #pragma unroll
  for (int i = 0; i < 8; ++i) {
    int r = row0 + trow * 8 + i;
    drow[i] = (MODE == 2) ? dest_row_cross(r) : dest_row_self(r);
  }

  #pragma unroll
  for (int m = 0; m < NMAT; ++m) {
    const float* Bm = (m == 0) ? B0 : ((m == 1) ? B1 : B2);
    float*       Om = (m == 0) ? O0 : ((m == 1) ? O1 : O2);
    float acc[8][4];
    #pragma unroll
    for (int i = 0; i < 8; ++i)
      #pragma unroll
      for (int j = 0; j < 4; ++j) acc[i][j] = 0.f;

    for (int kc = 0; kc < 2; ++kc) {
      __syncthreads();
      { // load B chunk [64][128]
        int kb = tid >> 2;
        int cb = (tid & 3) * 4;
        #pragma unroll
        for (int i = 0; i < 8; ++i) {
          int c = cb + i * 16;
          f4 b = *(const f4*)(Bm + (size_t)(kc * 64 + kb) * Dm + c);
          *(f4*)&Bs[kb][c] = b;
        }
      }
      __syncthreads();
      #pragma unroll 4
      for (int k = 0; k < 64; ++k) {
        int kg = kc * 64 + k;
        f4 a0 = *(const f4*)&At[kg][trow * 8];
        f4 a1 = *(const f4*)&At[kg][trow * 8 + 4];
        f4 b  = *(const f4*)&Bs[k][tcol * 4];
        #pragma unroll
        for (int j = 0; j < 4; ++j) {
          acc[0][j] += a0[0] * b[j];
          acc[1][j] += a0[1] * b[j];
          acc[2][j] += a0[2] * b[j];
          acc[3][j] += a0[3] * b[j];
          acc[4][j] += a1[0] * b[j];
          acc[5][j] += a1[1] * b[j];
          acc[6][j] += a1[2] * b[j];
          acc[7][j] += a1[3] * b[j];
        }
      }
    }
    #pragma unroll
    for (int i = 0; i < 8; ++i) {
      f4 o;
      o[0] = acc[i][0]; o[1] = acc[i][1]; o[2] = acc[i][2]; o[3] = acc[i][3];
      *(f4*)(Om + (size_t)drow[i] * Dm + tcol * 4) = o;
    }
  }
}

// ---------------------------------------------------------------------------
// Windowed attention. MM=1 self (256 keys), MM=2 cross (512 keys, view-
// interleaved). 512 threads, 32 queries/block, grid (8 qtiles, 384 windows).
// Writes output directly in token layout (inverse roll applied).
// ---------------------------------------------------------------------------
template<int MM>
__global__ __launch_bounds__(512, 2)
void attn_kernel(const float* __restrict__ Qw, const float* __restrict__ Kw,
                 const float* __restrict__ Vw, float* __restrict__ X)
{
  constexpr int KC = WSZ * MM;
  __shared__ float Qt[128][36];        // Q tile transposed [c][q]
  __shared__ float Stg[128 * 132];     // K chunk transposed [c][key] / V chunk [key][c]
  __shared__ float S[32][KC + 1];      // scores (+1 pad: conflict-free col reads)

  const int tid = threadIdx.x;
  const int bn  = blockIdx.y;
  const int q0  = blockIdx.x * 32;
  const int b   = bn >> 6;
  const int win = bn & 63;
  const int wy  = win >> 3, wx = win & 7;

  { // stage Q transposed
    const float* Qbase = Qw + ((size_t)bn * WSZ + q0) * Dm;
    #pragma unroll
    for (int j = 0; j < 2; ++j) {
      int id  = tid + j * 512;
      int row = id >> 5;
      int c   = (id & 31) * 4;
      f4 a = *(const f4*)(Qbase + row * Dm + c);
      Qt[c + 0][row] = a[0]; Qt[c + 1][row] = a[1];
      Qt[c + 2][row] = a[2]; Qt[c + 3][row] = a[3];
    }
  }

  // shift-window mask region id of a token index within the mask image
  auto region = [&](int t) -> int {
    int rh = (wy == 7) ? (((t >> 4) >= 8) ? 2 : 1) : 0;
    int rw = (wx == 7) ? (((t & 15) >= 8) ? 2 : 1) : 0;
    return rh * 3 + rw;
  };

  // ---- phase 1: S = Q K^T * scale + mask ----
  const int kg = tid & 31;       // keys kg*4 .. +3 (within 128-chunk)
  const int qg = tid >> 5;       // queries qg*2, qg*2+1
  const int rq0 = region(q0 + qg * 2);
  const int rq1 = region(q0 + qg * 2 + 1);

  for (int ch = 0; ch < KC / 128; ++ch) {
    __syncthreads();
    #pragma unroll
    for (int j = 0; j < 8; ++j) {  // stage K chunk transposed
      int id  = tid + j * 512;
      int key = id >> 5;
      int c   = (id & 31) * 4;
      f4 kvv = *(const f4*)(Kw + ((size_t)bn * KC + ch * 128 + key) * Dm + c);
      Stg[(c + 0) * 132 + key] = kvv[0];
      Stg[(c + 1) * 132 + key] = kvv[1];
      Stg[(c + 2) * 132 + key] = kvv[2];
      Stg[(c + 3) * 132 + key] = kvv[3];
    }
    __syncthreads();
    float a00 = 0, a01 = 0, a02 = 0, a03 = 0;
    float a10 = 0, a11 = 0, a12 = 0, a13 = 0;
    #pragma unroll 4
    for (int c = 0; c < 128; ++c) {
      f2 qv  = *(const f2*)&Qt[c][qg * 2];
      f4 kv4 = *(const f4*)&Stg[c * 132 + kg * 4];
      a00 += qv[0] * kv4[0]; a01 += qv[0] * kv4[1];
      a02 += qv[0] * kv4[2]; a03 += qv[0] * kv4[3];
      a10 += qv[1] * kv4[0]; a11 += qv[1] * kv4[1];
      a12 += qv[1] * kv4[2]; a13 += qv[1] * kv4[3];
    }
    float s0[4] = {a00, a01, a02, a03};
    float s1[4] = {a10, a11, a12, a13};
    #pragma unroll
    for (int j = 0; j < 4; ++j) {
      int kk = ch * 128 + kg * 4 + j;
      int rk = region(kk & 255);          // cross: reference tiles mask, col = kk % 256
      S[qg * 2 + 0][kk] = s0[j] * SCALE + ((rq0 == rk) ? 0.f : -100.f);
      S[qg * 2 + 1][kk] = s1[j] * SCALE + ((rq1 == rk) ? 0.f : -100.f);
    }
  }
  __syncthreads();

  // ---- softmax (16 lanes per row) ----
  {
    int row = tid >> 4, l = tid & 15;
    float mx = -1e30f;
    for (int k = l; k < KC; k += 16) mx = fmaxf(mx, S[row][k]);
    #pragma unroll
    for (int msk = 1; msk < 16; msk <<= 1) mx = fmaxf(mx, __shfl_xor(mx, msk));
    float sum = 0.f;
    for (int k = l; k < KC; k += 16) {
      float e = expf(S[row][k] - mx);
      S[row][k] = e;
      sum += e;
    }
    #pragma unroll
    for (int msk = 1; msk < 16; msk <<= 1) sum += __shfl_xor(sum, msk);
    float inv = 1.0f / sum;
    for (int k = l; k < KC; k += 16) S[row][k] *= inv;
  }

  // ---- phase 2: O = P V ----
  const int cg = tid & 31;   // out cols cg*4 .. +3
  const int rg = tid >> 5;   // out rows rg*2, rg*2+1
  float o00 = 0, o01 = 0, o02 = 0, o03 = 0;
  float o10 = 0, o11 = 0, o12 = 0, o13 = 0;
  for (int ch = 0; ch < KC / 128; ++ch) {
    __syncthreads();
    #pragma unroll
    for (int j = 0; j < 8; ++j) {  // stage V chunk plain [key][c]
      int id  = tid + j * 512;
      int key = id >> 5;
      int c   = (id & 31) * 4;
      f4 vv = *(const f4*)(Vw + ((size_t)bn * KC + ch * 128 + key) * Dm + c);
      *(f4*)&Stg[key * 132 + c] = vv;
    }
    __syncthreads();
    #pragma unroll 4
    for (int k = 0; k < 128; ++k) {
      int kk = ch * 128 + k;
      float p0 = S[rg * 2 + 0][kk];
      float p1 = S[rg * 2 + 1][kk];
      f4 vv = *(const f4*)&Stg[k * 132 + cg * 4];
      o00 += p0 * vv[0]; o01 += p0 * vv[1]; o02 += p0 * vv[2]; o03 += p0 * vv[3];
      o10 += p1 * vv[0]; o11 += p1 * vv[1]; o12 += p1 * vv[2]; o13 += p1 * vv[3];
    }
  }
  // write out in token layout (merge + roll back)
  #pragma unroll
  for (int i = 0; i < 2; ++i) {
    int t  = q0 + rg * 2 + i;
    int iy = t >> 4, ix = t & 15;
    int y = (wy * 16 + iy + 8) & 127;
    int x = (wx * 16 + ix + 8) & 127;
    f4 o;
    if (i == 0) { o[0] = o00; o[1] = o01; o[2] = o02; o[3] = o03; }
    else        { o[0] = o10; o[1] = o11; o[2] = o12; o[3] = o13; }
    *(f4*)(X + ((size_t)(b * TOK + y * IW + x)) * Dm + cg * 4) = o;
  }
}

// ---------------------------------------------------------------------------
// Out = [srcAdd +] LayerNorm(Xin @ Wm; g, b).  Same GEMM skeleton as proj.
// ---------------------------------------------------------------------------
template<bool ADD>
__global__ __launch_bounds__(256, 2)
void merge_ln_kernel(const float* __restrict__ Xin, const float* __restrict__ Wm,
                     const float* __restrict__ g, const float* __restrict__ bi,
                     const float* __restrict__ srcAdd, float* __restrict__ Out)
{
  __shared__ float At[128][68];
  __shared__ float Bs[64][132];
  const int tid  = threadIdx.x;
  const int row0 = blockIdx.x * 64;

  {
    const int tr = tid >> 2;
    const int tc = (tid & 3) * 4;
    const float* Ar = Xin + (size_t)(row0 + tr) * Dm;
    #pragma unroll
    for (int i = 0; i < 8; ++i) {
      int c = tc + i * 16;
      f4 a = *(const f4*)(Ar + c);
      At[c + 0][tr] = a[0]; At[c + 1][tr] = a[1];
      At[c + 2][tr] = a[2]; At[c + 3][tr] = a[3];
    }
  }

  const int tcol = tid & 31;
  const int trow = tid >> 5;
  float acc[8][4];
  #pragma unroll
  for (int i = 0; i < 8; ++i)
    #pragma unroll
    for (int j = 0; j < 4; ++j) acc[i][j] = 0.f;

  for (int kc = 0; kc < 2; ++kc) {
    __syncthreads();
    {
      int kb = tid >> 2;
      int cb = (tid & 3) * 4;
      #pragma unroll
      for (int i = 0; i < 8; ++i) {
        int c = cb + i * 16;
        f4 b = *(const f4*)(Wm + (size_t)(kc * 64 + kb) * Dm + c);
        *(f4*)&Bs[kb][c] = b;
      }
    }
    __syncthreads();
    #pragma unroll 4
    for (int k = 0; k < 64; ++k) {
      int kg = kc * 64 + k;
      f4 a0 = *(const f4*)&At[kg][trow * 8];
      f4 a1 = *(const f4*)&At[kg][trow * 8 + 4];
      f4 b  = *(const f4*)&Bs[k][tcol * 4];
      #pragma unroll
      for (int j = 0; j < 4; ++j) {
        acc[0][j] += a0[0] * b[j];
        acc[1][j] += a0[1] * b[j];
        acc[2][j] += a0[2] * b[j];
        acc[3][j] += a0[3] * b[j];
        acc[4][j] += a1[0] * b[j];
        acc[5][j] += a1[1] * b[j];
        acc[6][j] += a1[2] * b[j];
        acc[7][j] += a1[3] * b[j];
      }
    }
  }

  f4 g4 = *(const f4*)(g + tcol * 4);
  f4 b4 = *(const f4*)(bi + tcol * 4);
  #pragma unroll
  for (int i = 0; i < 8; ++i) {
    float s = acc[i][0] + acc[i][1] + acc[i][2] + acc[i][3];
    #pragma unroll
    for (int msk = 1; msk < 32; msk <<= 1) s += __shfl_xor(s, msk);
    float mu = s * (1.0f / 128.0f);
    float d0 = acc[i][0] - mu, d1 = acc[i][1] - mu;
    float d2 = acc[i][2] - mu, d3 = acc[i][3] - mu;
    float qs = d0 * d0 + d1 * d1 + d2 * d2 + d3 * d3;
    #pragma unroll
    for (int msk = 1; msk < 32; msk <<= 1) qs += __shfl_xor(qs, msk);
    float rstd = 1.0f / sqrtf(qs * (1.0f / 128.0f) + 1e-5f);
    int r = row0 + trow * 8 + i;
    f4 o;
    o[0] = d0 * rstd * g4[0] + b4[0];
    o[1] = d1 * rstd * g4[1] + b4[1];
    o[2] = d2 * rstd * g4[2] + b4[2];
    o[3] = d3 * rstd * g4[3] + b4[3];
    if (ADD) {
      f4 sv = *(const f4*)(srcAdd + (size_t)r * Dm + tcol * 4);
      o += sv;
    }
    *(f4*)(Out + (size_t)r * Dm + tcol * 4) = o;
  }
}

// ---------------------------------------------------------------------------
// Fused MLP pass: part[py] = gelu(concat(SRC,MSG) @ W1[:, py*256:+256]) @ W2[py*256:+256, :]
// 32 rows/block, W1/W2 streamed from L2.
// ---------------------------------------------------------------------------
__global__ __launch_bounds__(256, 2)
void mlp_kernel(const float* __restrict__ SRC, const float* __restrict__ MSG,
                const float* __restrict__ W1, const float* __restrict__ W2,
                float* __restrict__ part)
{
  __shared__ float At[256][36];  // concat rows transposed [k][row]
  __shared__ float Ht[256][36];  // gelu(hid) transposed [colchunk][row]
  const int tid  = threadIdx.x;
  const int row0 = blockIdx.x * 32;
  const int py   = blockIdx.y;

  #pragma unroll
  for (int j = 0; j < 8; ++j) {  // stage concat(SRC, MSG) transposed
    int id  = tid + j * 256;
    int row = id >> 6;
    int c   = (id & 63) * 4;
    const float* src = (c < 128) ? (SRC + (size_t)(row0 + row) * Dm + c)
                                 : (MSG + (size_t)(row0 + row) * Dm + (c - 128));
    f4 a = *(const f4*)src;
    At[c + 0][row] = a[0]; At[c + 1][row] = a[1];
    At[c + 2][row] = a[2]; At[c + 3][row] = a[3];
  }
  __syncthreads();

  // GEMM1: hid[32][256] for this pass's column chunk
  {
    const int tcol = tid & 63;   // chunk cols tcol*4
    const int trow = tid >> 6;   // rows trow*8 .. +7
    float acc[8][4];
    #pragma unroll
    for (int i = 0; i < 8; ++i)
      #pragma unroll
      for (int j = 0; j < 4; ++j) acc[i][j] = 0.f;
    const float* w1p = W1 + (size_t)py * 256 + tcol * 4;
    #pragma unroll 2
    for (int k = 0; k < 256; ++k) {
      f4 a0 = *(const f4*)&At[k][trow * 8];
      f4 a1 = *(const f4*)&At[k][trow * 8 + 4];
      f4 w  = *(const f4*)(w1p + (size_t)k * 1024);
      #pragma unroll
      for (int j = 0; j < 4; ++j) {
        acc[0][j] += a0[0] * w[j];
        acc[1][j] += a0[1] * w[j];
        acc[2][j] += a0[2] * w[j];
        acc[3][j] += a0[3] * w[j];
        acc[4][j] += a1[0] * w[j];
        acc[5][j] += a1[1] * w[j];
        acc[6][j] += a1[2] * w[j];
        acc[7][j] += a1[3] * w[j];
      }
    }
    #pragma unroll
    for (int i = 0; i < 8; ++i)
      #pragma unroll
      for (int j = 0; j < 4; ++j) {
        float xv = acc[i][j];
        Ht[tcol * 4 + j][trow * 8 + i] =
            0.5f * xv * (1.0f + erff(xv * 0.70710678118654752f));
      }
  }
  __syncthreads();

  // GEMM2: part tile [32][128]
  {
    const int tc2 = tid & 31;   // out cols tc2*4
    const int tr2 = tid >> 5;   // out rows tr2*4 .. +3
    float a2[4][4];
    #pragma unroll
    for (int i = 0; i < 4; ++i)
      #pragma unroll
      for (int j = 0; j < 4; ++j) a2[i][j] = 0.f;
    const float* w2p = W2 + (size_t)py * 256 * 128 + tc2 * 4;
    #pragma unroll 2
    for (int k = 0; k < 256; ++k) {
      f4 h = *(const f4*)&Ht[k][tr2 * 4];
      f4 w = *(const f4*)(w2p + (size_t)k * 128);
      #pragma unroll
      for (int j = 0; j < 4; ++j) {
        a2[0][j] += h[0] * w[j];
        a2[1][j] += h[1] * w[j];
        a2[2][j] += h[2] * w[j];
        a2[3][j] += h[3] * w[j];
      }
    }
    #pragma unroll
    for (int i = 0; i < 4; ++i) {
      f4 o;
      o[0] = a2[i][0]; o[1] = a2[i][1]; o[2] = a2[i][2]; o[3] = a2[i][3];
      *(f4*)(part + ((size_t)py * ROWS + row0 + tr2 * 4 + i) * Dm + tc2 * 4) = o;
    }
  }
}

// ---------------------------------------------------------------------------
// out = SRC + LN(sum_p part[p]); 8 rows/block, 32 lanes per row.
// ---------------------------------------------------------------------------
__global__ __launch_bounds__(256)
void final_kernel(const float* __restrict__ part, const float* __restrict__ SRC,
                  const float* __restrict__ g, const float* __restrict__ bi,
                  float* __restrict__ Out)
{
  const int tid = threadIdx.x;
  const int row = blockIdx.x * 8 + (tid >> 5);
  const int c   = (tid & 31) * 4;
  const size_t off = (size_t)row * Dm + c;
  const size_t stride = (size_t)ROWS * Dm;

  f4 v = *(const f4*)(part + off);
  v += *(const f4*)(part + stride + off);
  v += *(const f4*)(part + 2 * stride + off);
  v += *(const f4*)(part + 3 * stride + off);

  float s = v[0] + v[1] + v[2] + v[3];
  #pragma unroll
  for (int msk = 1; msk < 32; msk <<= 1) s += __shfl_xor(s, msk);
  float mu = s * (1.0f / 128.0f);
  f4 d = v - mu;
  float qs = d[0] * d[0] + d[1] * d[1] + d[2] * d[2] + d[3] * d[3];
  #pragma unroll
  for (int msk = 1; msk < 32; msk <<= 1) qs += __shfl_xor(qs, msk);
  float rstd = 1.0f / sqrtf(qs * (1.0f / 128.0f) + 1e-5f);

  f4 g4 = *(const f4*)(g + c);
  f4 b4 = *(const f4*)(bi + c);
  f4 sv = *(const f4*)(SRC + off);
  f4 o = d * rstd * g4 + b4 + sv;
  *(f4*)(Out + off) = o;
}

// ---------------------------------------------------------------------------
extern "C" void kernel_launch(void* const* d_in, const int* in_sizes, int n_in,
                              void* d_out, int out_size, void* d_ws, size_t ws_size,
                              hipStream_t stream)
{
  const float* source = (const float*)d_in[0];
  const float* kv     = (const float*)d_in[1];
  // d_in[2] attn_mask: reproduced on the fly
  const float* q1    = (const float*)d_in[3];
  const float* k1    = (const float*)d_in[4];
  const float* v1    = (const float*)d_in[5];
  const float* m1    = (const float*)d_in[6];
  const float* ln1g  = (const float*)d_in[7];
  const float* ln1b  = (const float*)d_in[8];
  const float* q2    = (const float*)d_in[9];
  const float* k2    = (const float*)d_in[10];
  const float* v2    = (const float*)d_in[11];
  const float* m2    = (const float*)d_in[12];
  const float* ln2ag = (const float*)d_in[13];
  const float* ln2ab = (const float*)d_in[14];
  const float* w1    = (const float*)d_in[15];
  const float* w2    = (const float*)d_in[16];
  const float* ln2bg = (const float*)d_in[17];
  const float* ln2bb = (const float*)d_in[18];

  float* ws   = (float*)d_ws;
  float* Qw   = ws;                                  // 12,582,912 f
  float* Kw   = Qw + (size_t)BN * WSZ * Dm;          // 25,165,824 f (cross-capable)
  float* Vw   = Kw + (size_t)BN * WSZ * Mv * Dm;     // 25,165,824 f
  float* SRCb = Vw + (size_t)BN * WSZ * Mv * Dm;     // 12,582,912 f
  float* part = Kw;                                  // 4*ROWS*Dm aliases Kw+Vw
  float* MSG2 = Qw;                                  // aliases Qw (free after attn2)
  float* X    = (float*)d_out;                       // attention scratch

  // 1. self qkv projections (windowed layout)
  proj_kernel<3, 0><<<ROWS / 64, 256, 0, stream>>>(source, q1, k1, v1, Qw, Kw, Vw);
  // 2. self window attention -> X (token layout)
  attn_kernel<1><<<dim3(8, BN), 512, 0, stream>>>(Qw, Kw, Vw, X);
  // 3. src = source + LN(X @ merge1)
  merge_ln_kernel<true><<<ROWS / 64, 256, 0, stream>>>(X, m1, ln1g, ln1b, source, SRCb);
  // 4. q2 projection (windowed)
  proj_kernel<1, 1><<<ROWS / 64, 256, 0, stream>>>(SRCb, q2, nullptr, nullptr,
                                                   Qw, nullptr, nullptr);
  // 5. k2/v2 projections (cross windowed, view-interleaved)
  proj_kernel<2, 2><<<KVROWS / 64, 256, 0, stream>>>(kv, k2, v2, nullptr,
                                                     Kw, Vw, nullptr);
  // 6. cross window attention -> X
  attn_kernel<2><<<dim3(8, BN), 512, 0, stream>>>(Qw, Kw, Vw, X);
  // 7. msg2 = LN(X @ merge2)
  merge_ln_kernel<false><<<ROWS / 64, 256, 0, stream>>>(X, m2, ln2ag, ln2ab,
                                                        nullptr, MSG2);
  // 8. fused MLP (4 column passes, split-K partials)
  mlp_kernel<<<dim3(ROWS / 32, 4), 256, 0, stream>>>(SRCb, MSG2, w1, w2, part);
  // 9. out = src + LN(sum partials)
  final_kernel<<<ROWS / 8, 256, 0, stream>>>(part, SRCb, ln2bg, ln2bb, (float*)d_out);
}

// Round 2
// 2454.741 us; speedup vs baseline: 1.2909x; 1.2909x over previous
//
#include <hip/hip_runtime.h>
#include <math.h>

// ---------------------------------------------------------------------------
// MultiViewFeatureTransformer — round 1: MLP converted to split-bf16 MFMA.
//  * MLP: single fused pass, hi/lo bf16 split (3 MFMA per fp32 product,
//    rel err ~2^-16), full hidden-1024 reduction in registers, LN+residual
//    fused in epilogue. No split-K partials, final_kernel removed.
//  * Weights pre-split into MFMA-fragment-linear hi/lo planes by prep kernel
//    (must rerun each launch: d_ws is re-poisoned).
//  * A-frags and B-frags share the same (lane,elem)->k enumeration, so the
//    result is correct under any internal hardware k-permutation.
//  * LDS planes XOR-swizzled ((row&7)<<2 on word idx) -> conflict-free
//    ds_read_b128 fragment reads.
// ---------------------------------------------------------------------------

typedef float f4 __attribute__((ext_vector_type(4)));
typedef float f2 __attribute__((ext_vector_type(2)));
typedef float f32x4 __attribute__((ext_vector_type(4)));
typedef short s16x8 __attribute__((ext_vector_type(8)));
typedef short s16x4 __attribute__((ext_vector_type(4)));
typedef unsigned short u16;

constexpr int Dm   = 128;
constexpr int IH   = 128, IW = 128;
constexpr int Bq   = 6;
constexpr int Mv   = 2;
constexpr int WSZ  = 256;
constexpr int TOK  = IH * IW;            // 16384
constexpr int ROWS = Bq * TOK;           // 98304
constexpr int KVROWS = Bq * Mv * TOK;    // 196608
constexpr int BN   = Bq * 64;            // 384
constexpr float SCALE = 0.08838834764831845f;  // 1/sqrt(128)

__device__ __forceinline__ u16 f2bf(float x) {
  union { float f; unsigned u; } v; v.f = x;
  unsigned r = v.u + 0x7fffu + ((v.u >> 16) & 1u);
  return (u16)(r >> 16);
}
__device__ __forceinline__ float bf2f(u16 h) {
  union { float f; unsigned u; } v; v.u = ((unsigned)h) << 16;
  return v.f;
}

// token row -> windowed row (roll by (-8,-8), 8x8 grid of 16x16 windows)
__device__ __forceinline__ int dest_row_self(int r) {
  int b = r >> 14;
  int p = r & 16383;
  int y = p >> 7, x = p & 127;
  int Y = (y + 120) & 127, X = (x + 120) & 127;
  int bn = (b << 6) + ((Y >> 4) << 3) + (X >> 4);
  int t  = ((Y & 15) << 4) + (X & 15);
  return bn * WSZ + t;
}

// kv row (b, view, spatial) -> cross windowed row: key index = t*Mv + view
__device__ __forceinline__ int dest_row_cross(int r) {
  int b  = r >> 15;
  int vi = (r >> 14) & 1;
  int p  = r & 16383;
  int y = p >> 7, x = p & 127;
  int Y = (y + 120) & 127, X = (x + 120) & 127;
  int bn = (b << 6) + ((Y >> 4) << 3) + (X >> 4);
  int t  = ((Y & 15) << 4) + (X & 15);
  return bn * (WSZ * Mv) + t * Mv + vi;
}

// ---------------------------------------------------------------------------
// Projection GEMM (unchanged from round 0, fp32 VALU — converted next round).
// ---------------------------------------------------------------------------
template<int NMAT, int MODE>
__global__ __launch_bounds__(256, 2)
void proj_kernel(const float* __restrict__ A,
                 const float* __restrict__ B0, const float* __restrict__ B1,
                 const float* __restrict__ B2,
                 float* __restrict__ O0, float* __restrict__ O1,
                 float* __restrict__ O2)
{
  __shared__ float At[128][68];   // A tile transposed [k][row]
  __shared__ float Bs[64][132];   // B k-chunk [k][c]
  const int tid  = threadIdx.x;
  const int row0 = blockIdx.x * 64;

  {
    const int tr = tid >> 2;
    const int tc = (tid & 3) * 4;
    const float* Ar = A + (size_t)(row0 + tr) * Dm;
    #pragma unroll
    for (int i = 0; i < 8; ++i) {
      int c = tc + i * 16;
      f4 a = *(const f4*)(Ar + c);
      At[c + 0][tr] = a[0];
      At[c + 1][tr] = a[1];
      At[c + 2][tr] = a[2];
      At[c + 3][tr] = a[3];
    }
  }

  const int tcol = tid & 31;
  const int trow = tid >> 5;

  int drow[8];
  #pragma unroll
  for (int i = 0; i < 8; ++i) {
    int r = row0 + trow * 8 + i;
    drow[i] = (MODE == 2) ? dest_row_cross(r) : dest_row_self(r);
  }

  #pragma unroll
  for (int m = 0; m < NMAT; ++m) {
    const float* Bm = (m == 0) ? B0 : ((m == 1) ? B1 : B2);
    float*       Om = (m == 0) ? O0 : ((m == 1) ? O1 : O2);
    float acc[8][4];
    #pragma unroll
    for (int i = 0; i < 8; ++i)
      #pragma unroll
      for (int j = 0; j < 4; ++j) acc[i][j] = 0.f;

    for (int kc = 0; kc < 2; ++kc) {
      __syncthreads();
      {
        int kb = tid >> 2;
        int cb = (tid & 3) * 4;
        #pragma unroll
        for (int i = 0; i < 8; ++i) {
          int c = cb + i * 16;
          f4 b = *(const f4*)(Bm + (size_t)(kc * 64 + kb) * Dm + c);
          *(f4*)&Bs[kb][c] = b;
        }
      }
      __syncthreads();
      #pragma unroll 4
      for (int k = 0; k < 64; ++k) {
        int kg = kc * 64 + k;
        f4 a0 = *(const f4*)&At[kg][trow * 8];
        f4 a1 = *(const f4*)&At[kg][trow * 8 + 4];
        f4 b  = *(const f4*)&Bs[k][tcol * 4];
        #pragma unroll
        for (int j = 0; j < 4; ++j) {
          acc[0][j] += a0[0] * b[j];
          acc[1][j] += a0[1] * b[j];
          acc[2][j] += a0[2] * b[j];
          acc[3][j] += a0[3] * b[j];
          acc[4][j] += a1[0] * b[j];
          acc[5][j] += a1[1] * b[j];
          acc[6][j] += a1[2] * b[j];
          acc[7][j] += a1[3] * b[j];
        }
      }
    }
    #pragma unroll
    for (int i = 0; i < 8; ++i) {
      f4 o;
      o[0] = acc[i][0]; o[1] = acc[i][1]; o[2] = acc[i][2]; o[3] = acc[i][3];
      *(f4*)(Om + (size_t)drow[i] * Dm + tcol * 4) = o;
    }
  }
}

// ---------------------------------------------------------------------------
// Windowed attention (unchanged from round 0).
// ---------------------------------------------------------------------------
template<int MM>
__global__ __launch_bounds__(512, 2)
void attn_kernel(const float* __restrict__ Qw, const float* __restrict__ Kw,
                 const float* __restrict__ Vw, float* __restrict__ X)
{
  constexpr int KC = WSZ * MM;
  __shared__ float Qt[128][36];
  __shared__ float Stg[128 * 132];
  __shared__ float S[32][KC + 1];

  const int tid = threadIdx.x;
  const int bn  = blockIdx.y;
  const int q0  = blockIdx.x * 32;
  const int b   = bn >> 6;
  const int win = bn & 63;
  const int wy  = win >> 3, wx = win & 7;

  {
    const float* Qbase = Qw + ((size_t)bn * WSZ + q0) * Dm;
    #pragma unroll
    for (int j = 0; j < 2; ++j) {
      int id  = tid + j * 512;
      int row = id >> 5;
      int c   = (id & 31) * 4;
      f4 a = *(const f4*)(Qbase + row * Dm + c);
      Qt[c + 0][row] = a[0]; Qt[c + 1][row] = a[1];
      Qt[c + 2][row] = a[2]; Qt[c + 3][row] = a[3];
    }
  }

  auto region = [&](int t) -> int {
    int rh = (wy == 7) ? (((t >> 4) >= 8) ? 2 : 1) : 0;
    int rw = (wx == 7) ? (((t & 15) >= 8) ? 2 : 1) : 0;
    return rh * 3 + rw;
  };

  const int kg = tid & 31;
  const int qg = tid >> 5;
  const int rq0 = region(q0 + qg * 2);
  const int rq1 = region(q0 + qg * 2 + 1);

  for (int ch = 0; ch < KC / 128; ++ch) {
    __syncthreads();
    #pragma unroll
    for (int j = 0; j < 8; ++j) {
      int id  = tid + j * 512;
      int key = id >> 5;
      int c   = (id & 31) * 4;
      f4 kvv = *(const f4*)(Kw + ((size_t)bn * KC + ch * 128 + key) * Dm + c);
      Stg[(c + 0) * 132 + key] = kvv[0];
      Stg[(c + 1) * 132 + key] = kvv[1];
      Stg[(c + 2) * 132 + key] = kvv[2];
      Stg[(c + 3) * 132 + key] = kvv[3];
    }
    __syncthreads();
    float a00 = 0, a01 = 0, a02 = 0, a03 = 0;
    float a10 = 0, a11 = 0, a12 = 0, a13 = 0;
    #pragma unroll 4
    for (int c = 0; c < 128; ++c) {
      f2 qv  = *(const f2*)&Qt[c][qg * 2];
      f4 kv4 = *(const f4*)&Stg[c * 132 + kg * 4];
      a00 += qv[0] * kv4[0]; a01 += qv[0] * kv4[1];
      a02 += qv[0] * kv4[2]; a03 += qv[0] * kv4[3];
      a10 += qv[1] * kv4[0]; a11 += qv[1] * kv4[1];
      a12 += qv[1] * kv4[2]; a13 += qv[1] * kv4[3];
    }
    float s0[4] = {a00, a01, a02, a03};
    float s1[4] = {a10, a11, a12, a13};
    #pragma unroll
    for (int j = 0; j < 4; ++j) {
      int kk = ch * 128 + kg * 4 + j;
      int rk = region(kk & 255);
      S[qg * 2 + 0][kk] = s0[j] * SCALE + ((rq0 == rk) ? 0.f : -100.f);
      S[qg * 2 + 1][kk] = s1[j] * SCALE + ((rq1 == rk) ? 0.f : -100.f);
    }
  }
  __syncthreads();

  {
    int row = tid >> 4, l = tid & 15;
    float mx = -1e30f;
    for (int k = l; k < KC; k += 16) mx = fmaxf(mx, S[row][k]);
    #pragma unroll
    for (int msk = 1; msk < 16; msk <<= 1) mx = fmaxf(mx, __shfl_xor(mx, msk));
    float sum = 0.f;
    for (int k = l; k < KC; k += 16) {
      float e = expf(S[row][k] - mx);
      S[row][k] = e;
      sum += e;
    }
    #pragma unroll
    for (int msk = 1; msk < 16; msk <<= 1) sum += __shfl_xor(sum, msk);
    float inv = 1.0f / sum;
    for (int k = l; k < KC; k += 16) S[row][k] *= inv;
  }

  const int cg = tid & 31;
  const int rg = tid >> 5;
  float o00 = 0, o01 = 0, o02 = 0, o03 = 0;
  float o10 = 0, o11 = 0, o12 = 0, o13 = 0;
  for (int ch = 0; ch < KC / 128; ++ch) {
    __syncthreads();
    #pragma unroll
    for (int j = 0; j < 8; ++j) {
      int id  = tid + j * 512;
      int key = id >> 5;
      int c   = (id & 31) * 4;
      f4 vv = *(const f4*)(Vw + ((size_t)bn * KC + ch * 128 + key) * Dm + c);
      *(f4*)&Stg[key * 132 + c] = vv;
    }
    __syncthreads();
    #pragma unroll 4
    for (int k = 0; k < 128; ++k) {
      int kk = ch * 128 + k;
      float p0 = S[rg * 2 + 0][kk];
      float p1 = S[rg * 2 + 1][kk];
      f4 vv = *(const f4*)&Stg[k * 132 + cg * 4];
      o00 += p0 * vv[0]; o01 += p0 * vv[1]; o02 += p0 * vv[2]; o03 += p0 * vv[3];
      o10 += p1 * vv[0]; o11 += p1 * vv[1]; o12 += p1 * vv[2]; o13 += p1 * vv[3];
    }
  }
  #pragma unroll
  for (int i = 0; i < 2; ++i) {
    int t  = q0 + rg * 2 + i;
    int iy = t >> 4, ix = t & 15;
    int y = (wy * 16 + iy + 8) & 127;
    int x = (wx * 16 + ix + 8) & 127;
    f4 o;
    if (i == 0) { o[0] = o00; o[1] = o01; o[2] = o02; o[3] = o03; }
    else        { o[0] = o10; o[1] = o11; o[2] = o12; o[3] = o13; }
    *(f4*)(X + ((size_t)(b * TOK + y * IW + x)) * Dm + cg * 4) = o;
  }
}

// ---------------------------------------------------------------------------
// Out = [srcAdd +] LayerNorm(Xin @ Wm; g, b)  (unchanged from round 0).
// ---------------------------------------------------------------------------
template<bool ADD>
__global__ __launch_bounds__(256, 2)
void merge_ln_kernel(const float* __restrict__ Xin, const float* __restrict__ Wm,
                     const float* __restrict__ g, const float* __restrict__ bi,
                     const float* __restrict__ srcAdd, float* __restrict__ Out)
{
  __shared__ float At[128][68];
  __shared__ float Bs[64][132];
  const int tid  = threadIdx.x;
  const int row0 = blockIdx.x * 64;

  {
    const int tr = tid >> 2;
    const int tc = (tid & 3) * 4;
    const float* Ar = Xin + (size_t)(row0 + tr) * Dm;
    #pragma unroll
    for (int i = 0; i < 8; ++i) {
      int c = tc + i * 16;
      f4 a = *(const f4*)(Ar + c);
      At[c + 0][tr] = a[0]; At[c + 1][tr] = a[1];
      At[c + 2][tr] = a[2]; At[c + 3][tr] = a[3];
    }
  }

  const int tcol = tid & 31;
  const int trow = tid >> 5;
  float acc[8][4];
  #pragma unroll
  for (int i = 0; i < 8; ++i)
    #pragma unroll
    for (int j = 0; j < 4; ++j) acc[i][j] = 0.f;

  for (int kc = 0; kc < 2; ++kc) {
    __syncthreads();
    {
      int kb = tid >> 2;
      int cb = (tid & 3) * 4;
      #pragma unroll
      for (int i = 0; i < 8; ++i) {
        int c = cb + i * 16;
        f4 b = *(const f4*)(Wm + (size_t)(kc * 64 + kb) * Dm + c);
        *(f4*)&Bs[kb][c] = b;
      }
    }
    __syncthreads();
    #pragma unroll 4
    for (int k = 0; k < 64; ++k) {
      int kg = kc * 64 + k;
      f4 a0 = *(const f4*)&At[kg][trow * 8];
      f4 a1 = *(const f4*)&At[kg][trow * 8 + 4];
      f4 b  = *(const f4*)&Bs[k][tcol * 4];
      #pragma unroll
      for (int j = 0; j < 4; ++j) {
        acc[0][j] += a0[0] * b[j];
        acc[1][j] += a0[1] * b[j];
        acc[2][j] += a0[2] * b[j];
        acc[3][j] += a0[3] * b[j];
        acc[4][j] += a1[0] * b[j];
        acc[5][j] += a1[1] * b[j];
        acc[6][j] += a1[2] * b[j];
        acc[7][j] += a1[3] * b[j];
      }
    }
  }

  f4 g4 = *(const f4*)(g + tcol * 4);
  f4 b4 = *(const f4*)(bi + tcol * 4);
  #pragma unroll
  for (int i = 0; i < 8; ++i) {
    float s = acc[i][0] + acc[i][1] + acc[i][2] + acc[i][3];
    #pragma unroll
    for (int msk = 1; msk < 32; msk <<= 1) s += __shfl_xor(s, msk);
    float mu = s * (1.0f / 128.0f);
    float d0 = acc[i][0] - mu, d1 = acc[i][1] - mu;
    float d2 = acc[i][2] - mu, d3 = acc[i][3] - mu;
    float qs = d0 * d0 + d1 * d1 + d2 * d2 + d3 * d3;
    #pragma unroll
    for (int msk = 1; msk < 32; msk <<= 1) qs += __shfl_xor(qs, msk);
    float rstd = 1.0f / sqrtf(qs * (1.0f / 128.0f) + 1e-5f);
    int r = row0 + trow * 8 + i;
    f4 o;
    o[0] = d0 * rstd * g4[0] + b4[0];
    o[1] = d1 * rstd * g4[1] + b4[1];
    o[2] = d2 * rstd * g4[2] + b4[2];
    o[3] = d3 * rstd * g4[3] + b4[3];
    if (ADD) {
      f4 sv = *(const f4*)(srcAdd + (size_t)r * Dm + tcol * 4);
      o += sv;
    }
    *(f4*)(Out + (size_t)r * Dm + tcol * 4) = o;
  }
}

// ---------------------------------------------------------------------------
// Weight prep: split W1 (256x1024) / W2 (1024x128) into bf16 hi/lo planes in
// MFMA B-fragment-linear order.
//  W1 frag id = ((((c*8+ct)*8+ks)*64)+lane)*8+i ; k=ks*32+(lane>>4)*8+i,
//               col = c*128+ct*16+(lane&15)
//  W2 frag id = ((((c*4+ks)*8+ct)*64)+lane)*8+i ; k=c*128+ks*32+(lane>>4)*8+i,
//               col = ct*16+(lane&15)
// ---------------------------------------------------------------------------
__global__ __launch_bounds__(256)
void prep_weights(const float* __restrict__ W1, const float* __restrict__ W2,
                  u16* __restrict__ w1h, u16* __restrict__ w1l,
                  u16* __restrict__ w2h, u16* __restrict__ w2l)
{
  int id = blockIdx.x * 256 + threadIdx.x;
  if (id < 262144) {
    int i  = id & 7;
    int ln = (id >> 3) & 63;
    int ks = (id >> 9) & 7;
    int ct = (id >> 12) & 7;
    int c  = id >> 15;
    int k   = ks * 32 + (ln >> 4) * 8 + i;
    int col = c * 128 + ct * 16 + (ln & 15);
    float v = W1[(size_t)k * 1024 + col];
    u16 h = f2bf(v);
    w1h[id] = h;
    w1l[id] = f2bf(v - bf2f(h));
  } else {
    int id2 = id - 262144;     // < 131072
    int i  = id2 & 7;
    int ln = (id2 >> 3) & 63;
    int ct = (id2 >> 9) & 7;
    int ks = (id2 >> 12) & 3;
    int c  = id2 >> 14;
    int k   = c * 128 + ks * 32 + (ln >> 4) * 8 + i;
    int col = ct * 16 + (ln & 15);
    float v = W2[(size_t)k * 128 + col];
    u16 h = f2bf(v);
    w2h[id2] = h;
    w2l[id2] = f2bf(v - bf2f(h));
  }
}

// ---------------------------------------------------------------------------
// Fused MLP, split-bf16 MFMA:
//   out = SRC + LN( gelu(concat(SRC,MSG) @ W1) @ W2 )
// 64 rows/block, 512 threads (8 waves: rt = w&3 row-tile, ctg = w>>2 col half).
// Hidden processed in 8 chunks of 128; out acc [4 tiles x f32x4] in registers.
// LDS: X hi/lo planes (64x256 bf16, swizzled) + H hi/lo (64x128) = 96 KB.
// ---------------------------------------------------------------------------
__global__ __launch_bounds__(512)
void mlp_mfma_kernel(const float* __restrict__ SRC, const float* __restrict__ MSG,
                     const u16* __restrict__ w1h, const u16* __restrict__ w1l,
                     const u16* __restrict__ w2h, const u16* __restrict__ w2l,
                     const float* __restrict__ g, const float* __restrict__ bi,
                     float* __restrict__ Out)
{
  __shared__ __align__(16) u16 Xh[64 * 256];
  __shared__ __align__(16) u16 Xl[64 * 256];
  __shared__ __align__(16) u16 Hh[64 * 128];
  __shared__ __align__(16) u16 Hl[64 * 128];

  const int tid  = threadIdx.x;
  const int row0 = blockIdx.x * 64;
  const int l    = tid & 63;
  const int w    = tid >> 6;
  const int rt   = w & 3;
  const int ctg  = w >> 2;

  // ---- stage X = concat(SRC, MSG), split hi/lo, swizzled ----
  #pragma unroll
  for (int s = 0; s < 8; ++s) {
    int slot = tid + s * 512;
    int row  = slot >> 6;
    int c4   = (slot & 63) * 4;
    const float* p = (c4 < 128) ? (SRC + (size_t)(row0 + row) * Dm + c4)
                                : (MSG + (size_t)(row0 + row) * Dm + (c4 - 128));
    f4 a = *(const f4*)p;
    s16x4 hv, lv;
    #pragma unroll
    for (int i = 0; i < 4; ++i) {
      u16 h = f2bf(a[i]);
      hv[i] = (short)h;
      lv[i] = (short)f2bf(a[i] - bf2f(h));
    }
    int word = row * 128 + ((c4 >> 1) ^ ((row & 7) << 2));
    *(s16x4*)&Xh[word * 2] = hv;
    *(s16x4*)&Xl[word * 2] = lv;
  }

  f32x4 acc[4];
  #pragma unroll
  for (int i = 0; i < 4; ++i) acc[i] = (f32x4)(0.f);

  const int swz  = (l & 7) << 2;          // = ((arow&7)<<2), since arow&7 == l&7
  const int arow = rt * 16 + (l & 15);    // A-frag row
  const int kgrp = (l >> 4) * 8;          // A/B-frag k sub-offset

  __syncthreads();

  for (int c = 0; c < 8; ++c) {
    // ---- GEMM1: hid chunk [64][128] = X[64][256] @ W1[:, c*128..+128] ----
    f32x4 acc1[4];
    #pragma unroll
    for (int i = 0; i < 4; ++i) acc1[i] = (f32x4)(0.f);
    #pragma unroll 2
    for (int ks = 0; ks < 8; ++ks) {
      int k0 = ks * 32 + kgrp;
      int word = arow * 128 + ((k0 >> 1) ^ swz);
      s16x8 ah = *(const s16x8*)&Xh[word * 2];
      s16x8 al = *(const s16x8*)&Xl[word * 2];
      #pragma unroll
      for (int t = 0; t < 4; ++t) {
        int ct = ctg * 4 + t;
        size_t fo = (size_t)(((c * 8 + ct) * 8 + ks) * 64 + l) * 8;
        s16x8 bh = *(const s16x8*)(w1h + fo);
        s16x8 bl = *(const s16x8*)(w1l + fo);
        acc1[t] = __builtin_amdgcn_mfma_f32_16x16x32_bf16(ah, bh, acc1[t], 0, 0, 0);
        acc1[t] = __builtin_amdgcn_mfma_f32_16x16x32_bf16(ah, bl, acc1[t], 0, 0, 0);
        acc1[t] = __builtin_amdgcn_mfma_f32_16x16x32_bf16(al, bh, acc1[t], 0, 0, 0);
      }
    }
    // ---- gelu + hi/lo split into H planes ----
    __syncthreads();   // WAR vs previous chunk's GEMM2 reads
    #pragma unroll
    for (int t = 0; t < 4; ++t) {
      int col = (ctg * 4 + t) * 16 + (l & 15);
      #pragma unroll
      for (int j = 0; j < 4; ++j) {
        int row = rt * 16 + (l >> 4) * 4 + j;   // verified D mapping
        float x = acc1[t][j];
        float ge = 0.5f * x * (1.0f + erff(x * 0.70710678118654752f));
        u16 h  = f2bf(ge);
        u16 lo = f2bf(ge - bf2f(h));
        int word = row * 64 + ((col >> 1) ^ ((row & 7) << 2));
        int idx = word * 2 + (col & 1);
        Hh[idx] = h;
        Hl[idx] = lo;
      }
    }
    __syncthreads();
    // ---- GEMM2: acc += hidchunk[64][128] @ W2[c*128..+128, :] ----
    #pragma unroll
    for (int ks = 0; ks < 4; ++ks) {
      int k0 = ks * 32 + kgrp;
      int word = arow * 64 + ((k0 >> 1) ^ swz);
      s16x8 ah = *(const s16x8*)&Hh[word * 2];
      s16x8 al = *(const s16x8*)&Hl[word * 2];
      #pragma unroll
      for (int t = 0; t < 4; ++t) {
        int ct = ctg * 4 + t;
        size_t fo = (size_t)(((c * 4 + ks) * 8 + ct) * 64 + l) * 8;
        s16x8 bh = *(const s16x8*)(w2h + fo);
        s16x8 bl = *(const s16x8*)(w2l + fo);
        acc[t] = __builtin_amdgcn_mfma_f32_16x16x32_bf16(ah, bh, acc[t], 0, 0, 0);
        acc[t] = __builtin_amdgcn_mfma_f32_16x16x32_bf16(ah, bl, acc[t], 0, 0, 0);
        acc[t] = __builtin_amdgcn_mfma_f32_16x16x32_bf16(al, bh, acc[t], 0, 0, 0);
      }
    }
  }

  // ---- epilogue: out = SRC + LN(acc) ----
  __syncthreads();
  float* ob = (float*)Xh;   // 64x128 f32 = 32 KB, reuse X hi plane
  #pragma unroll
  for (int t = 0; t < 4; ++t) {
    int col = (ctg * 4 + t) * 16 + (l & 15);
    #pragma unroll
    for (int j = 0; j < 4; ++j) {
      int row = rt * 16 + (l >> 4) * 4 + j;
      ob[row * 128 + col] = acc[t][j];
    }
  }
  __syncthreads();
  {
    int row = tid >> 3, sub = tid & 7;
    const float* rp = ob + row * 128;
    f4 v[4];
    #pragma unroll
    for (int s = 0; s < 4; ++s) v[s] = *(const f4*)(rp + sub * 4 + s * 32);
    float sm = 0.f;
    #pragma unroll
    for (int s = 0; s < 4; ++s) sm += v[s][0] + v[s][1] + v[s][2] + v[s][3];
    sm += __shfl_xor(sm, 1); sm += __shfl_xor(sm, 2); sm += __shfl_xor(sm, 4);
    float mu = sm * (1.0f / 128.0f);
    float qs = 0.f;
    #pragma unroll
    for (int s = 0; s < 4; ++s) {
      v[s] -= mu;
      qs += v[s][0] * v[s][0] + v[s][1] * v[s][1] + v[s][2] * v[s][2] + v[s][3] * v[s][3];
    }
    qs += __shfl_xor(qs, 1); qs += __shfl_xor(qs, 2); qs += __shfl_xor(qs, 4);
    float rstd = 1.0f / sqrtf(qs * (1.0f / 128.0f) + 1e-5f);
    #pragma unroll
    for (int s = 0; s < 4; ++s) {
      int cc = sub * 4 + s * 32;
      f4 g4 = *(const f4*)(g + cc);
      f4 b4 = *(const f4*)(bi + cc);
      f4 rv = *(const f4*)(SRC + (size_t)(row0 + row) * Dm + cc);
      f4 o = v[s] * rstd * g4 + b4 + rv;
      *(f4*)(Out + (size_t)(row0 + row) * Dm + cc) = o;
    }
  }
}

// ---------------------------------------------------------------------------
extern "C" void kernel_launch(void* const* d_in, const int* in_sizes, int n_in,
                              void* d_out, int out_size, void* d_ws, size_t ws_size,
                              hipStream_t stream)
{
  const float* source = (const float*)d_in[0];
  const float* kv     = (const float*)d_in[1];
  // d_in[2] attn_mask: reproduced on the fly
  const float* q1    = (const float*)d_in[3];
  const float* k1    = (const float*)d_in[4];
  const float* v1    = (const float*)d_in[5];
  const float* m1    = (const float*)d_in[6];
  const float* ln1g  = (const float*)d_in[7];
  const float* ln1b  = (const float*)d_in[8];
  const float* q2    = (const float*)d_in[9];
  const float* k2    = (const float*)d_in[10];
  const float* v2    = (const float*)d_in[11];
  const float* m2    = (const float*)d_in[12];
  const float* ln2ag = (const float*)d_in[13];
  const float* ln2ab = (const float*)d_in[14];
  const float* w1    = (const float*)d_in[15];
  const float* w2    = (const float*)d_in[16];
  const float* ln2bg = (const float*)d_in[17];
  const float* ln2bb = (const float*)d_in[18];

  float* ws   = (float*)d_ws;
  float* Qw   = ws;                                  // [BN*256*128]
  float* Kw   = Qw + (size_t)BN * WSZ * Dm;          // [BN*512*128]
  float* Vw   = Kw + (size_t)BN * WSZ * Mv * Dm;     // [BN*512*128]
  float* SRCb = Vw + (size_t)BN * WSZ * Mv * Dm;     // [ROWS*128]
  float* MSG2 = Qw;                                  // aliases Qw (free after attn2)
  float* X    = (float*)d_out;                       // attention scratch

  // split-weight planes alias Vw (free after cross-attn; prep runs after step 7)
  u16* w1h = (u16*)Vw;
  u16* w1l = w1h + 262144;
  u16* w2h = w1l + 262144;
  u16* w2l = w2h + 131072;

  // 1. self qkv projections (windowed layout)
  proj_kernel<3, 0><<<ROWS / 64, 256, 0, stream>>>(source, q1, k1, v1, Qw, Kw, Vw);
  // 2. self window attention -> X (token layout)
  attn_kernel<1><<<dim3(8, BN), 512, 0, stream>>>(Qw, Kw, Vw, X);
  // 3. src = source + LN(X @ merge1)
  merge_ln_kernel<true><<<ROWS / 64, 256, 0, stream>>>(X, m1, ln1g, ln1b, source, SRCb);
  // 4. q2 projection (windowed)
  proj_kernel<1, 1><<<ROWS / 64, 256, 0, stream>>>(SRCb, q2, nullptr, nullptr,
                                                   Qw, nullptr, nullptr);
  // 5. k2/v2 projections (cross windowed, view-interleaved)
  proj_kernel<2, 2><<<KVROWS / 64, 256, 0, stream>>>(kv, k2, v2, nullptr,
                                                     Kw, Vw, nullptr);
  // 6. cross window attention -> X
  attn_kernel<2><<<dim3(8, BN), 512, 0, stream>>>(Qw, Kw, Vw, X);
  // 7. msg2 = LN(X @ merge2)
  merge_ln_kernel<false><<<ROWS / 64, 256, 0, stream>>>(X, m2, ln2ag, ln2ab,
                                                        nullptr, MSG2);
  // 8. split W1/W2 into MFMA-fragment hi/lo planes (rerun every launch)
  prep_weights<<<1536, 256, 0, stream>>>(w1, w2, w1h, w1l, w2h, w2l);
  // 9. fused MLP (MFMA) + LN + residual -> d_out
  mlp_mfma_kernel<<<ROWS / 64, 512, 0, stream>>>(SRCb, MSG2, w1h, w1l, w2h, w2l,
                                                 ln2bg, ln2bb, (float*)d_out);
}

// Round 3
// 2101.854 us; speedup vs baseline: 1.5077x; 1.1679x over previous
//
#include <hip/hip_runtime.h>
#include <math.h>

// ---------------------------------------------------------------------------
// MultiViewFeatureTransformer — round 2: everything on split-bf16 MFMA.
//  * hi/lo bf16 split everywhere (3 MFMA per fp32 product, rel err ~2^-16).
//  * Projections iterate OUTPUT (windowed) rows, gathering input rows via the
//    inverse roll map; emit Q/K as bf16 hi/lo planes and V as V^T planes
//    ([bn][d][key]) so attention PV gets key-contiguous fragments.
//  * Attention: flash-style per-window block (512 thr, 8 waves, 32 q/wave),
//    64-key chunks in swizzled LDS, online softmax in registers (D-layout,
//    16-lane shfl reduce), P hi/lo via wave-private LDS strips.
//  * Workspace = 301,989,888 B exactly (same as round 0):
//      A[50.3M]  Q planes  -> MSG2 (fp32) after attn2
//      B[100.7M] K planes  -> W1/W2/m2 frags after attn2; B2nd half hosts
//                             m1/q2 frags during phases 1-7 (self K = 1st half)
//      C[100.7M] V^T planes
//      D[50.3M]  transient weight frags / X (attn out, fp32)
//    SRCb lives in d_out (merge1 writes it; mlp reads+rewrites same rows).
// ---------------------------------------------------------------------------

typedef float f4 __attribute__((ext_vector_type(4)));
typedef float f32x4 __attribute__((ext_vector_type(4)));
typedef short s16x8 __attribute__((ext_vector_type(8)));
typedef short s16x4 __attribute__((ext_vector_type(4)));
typedef unsigned short u16;

constexpr int Dm   = 128;
constexpr int Bq   = 6;
constexpr int Mv   = 2;
constexpr int WSZ  = 256;
constexpr int TOK  = 16384;
constexpr int ROWS = Bq * TOK;           // 98304
constexpr int BN   = Bq * 64;            // 384
constexpr float SCALE = 0.08838834764831845f;  // 1/sqrt(128)

__device__ __forceinline__ u16 f2bf(float x) {
  union { float f; unsigned u; } v; v.f = x;
  unsigned r = v.u + 0x7fffu + ((v.u >> 16) & 1u);
  return (u16)(r >> 16);
}
__device__ __forceinline__ float bf2f(u16 h) {
  union { float f; unsigned u; } v; v.u = ((unsigned)h) << 16;
  return v.f;
}

// ---------------------------------------------------------------------------
// prep_dxd: split up to 3 [128x128] weights into MFMA B-fragment hi/lo planes.
// Per weight: h plane (16384 halves) then l plane at dst + widx*32768.
// frag id = ((ct*4+ks)*64+ln)*8+i ; k = ks*32+(ln>>4)*8+i ; col = ct*16+(ln&15)
// ---------------------------------------------------------------------------
__global__ __launch_bounds__(256)
void prep_dxd(const float* __restrict__ W0, const float* __restrict__ W1,
              const float* __restrict__ W2, u16* __restrict__ dst)
{
  int gid = blockIdx.x * 256 + threadIdx.x;
  int widx = gid >> 14;
  int id = gid & 16383;
  const float* W = (widx == 0) ? W0 : ((widx == 1) ? W1 : W2);
  int i = id & 7, ln = (id >> 3) & 63, ks = (id >> 9) & 3, ct = id >> 11;
  int k = ks * 32 + (ln >> 4) * 8 + i;
  int col = ct * 16 + (ln & 15);
  float v = W[k * 128 + col];
  u16 h = f2bf(v);
  u16* wp = dst + widx * 32768;
  wp[id] = h;
  wp[16384 + id] = f2bf(v - bf2f(h));
}

// ---------------------------------------------------------------------------
// prep W1 (256x1024), W2 (1024x128), m2 (128x128) frag planes.
// ---------------------------------------------------------------------------
__global__ __launch_bounds__(256)
void prep_w1w2m2(const float* __restrict__ W1, const float* __restrict__ W2,
                 const float* __restrict__ M2,
                 u16* __restrict__ w1h, u16* __restrict__ w1l,
                 u16* __restrict__ w2h, u16* __restrict__ w2l,
                 u16* __restrict__ m2h, u16* __restrict__ m2l)
{
  int id = blockIdx.x * 256 + threadIdx.x;
  if (id < 262144) {
    int i = id & 7, ln = (id >> 3) & 63, ks = (id >> 9) & 7;
    int ct = (id >> 12) & 7, c = id >> 15;
    int k = ks * 32 + (ln >> 4) * 8 + i;
    int col = c * 128 + ct * 16 + (ln & 15);
    float v = W1[(size_t)k * 1024 + col];
    u16 h = f2bf(v);
    w1h[id] = h; w1l[id] = f2bf(v - bf2f(h));
  } else if (id < 393216) {
    int id2 = id - 262144;
    int i = id2 & 7, ln = (id2 >> 3) & 63, ct = (id2 >> 9) & 7;
    int ks = (id2 >> 12) & 3, c = id2 >> 14;
    int k = c * 128 + ks * 32 + (ln >> 4) * 8 + i;
    int col = ct * 16 + (ln & 15);
    float v = W2[(size_t)k * 128 + col];
    u16 h = f2bf(v);
    w2h[id2] = h; w2l[id2] = f2bf(v - bf2f(h));
  } else {
    int id3 = id - 393216;  // < 16384
    int i = id3 & 7, ln = (id3 >> 3) & 63, ks = (id3 >> 9) & 3, ct = id3 >> 11;
    int k = ks * 32 + (ln >> 4) * 8 + i;
    int col = ct * 16 + (ln & 15);
    float v = M2[k * 128 + col];
    u16 h = f2bf(v);
    m2h[id3] = h; m2l[id3] = f2bf(v - bf2f(h));
  }
}

// ---------------------------------------------------------------------------
// Projection GEMM (MFMA): iterates OUTPUT rows (windowed order), gathers
// input rows via inverse roll map. 64 rows/block, 256 thr (4 waves).
// MODE 0: self qkv (m0->Q planes, m1->K planes, m2->Vt)
// MODE 1: q2 (m0->Q planes)
// MODE 2: cross kv (m0->K planes, m1->Vt), rows = bn*512 + t*2+vi
// ---------------------------------------------------------------------------
template<int MODE, int NMAT, int KC>
__global__ __launch_bounds__(256, 2)
void proj_mfma(const float* __restrict__ A,
               const u16* __restrict__ wh0, const u16* __restrict__ wl0,
               const u16* __restrict__ wh1, const u16* __restrict__ wl1,
               const u16* __restrict__ wh2, const u16* __restrict__ wl2,
               u16* __restrict__ q_h, u16* __restrict__ q_l,
               u16* __restrict__ k_h, u16* __restrict__ k_l,
               u16* __restrict__ v_h, u16* __restrict__ v_l)
{
  __shared__ __align__(16) u16 Ah[64 * 128];
  __shared__ __align__(16) u16 Al[64 * 128];
  __shared__ __align__(16) float ob[64 * 132];
  const int tid = threadIdx.x;
  const int l = tid & 63, w = tid >> 6;
  const int row0 = blockIdx.x * 64;

  // gather + split A rows
  #pragma unroll
  for (int it = 0; it < 8; ++it) {
    int task = tid + it * 256;
    int r = task >> 5, c4 = (task & 31) * 4;
    int rw = row0 + r;
    int src;
    if (MODE == 2) {
      int bn = rw >> 9, bb = bn >> 6, win = bn & 63, kk = rw & 511;
      int t = kk >> 1, vi = kk & 1;
      int y = (((win >> 3) << 4) + (t >> 4) + 8) & 127;
      int x = (((win & 7) << 4) + (t & 15) + 8) & 127;
      src = ((bb * 2 + vi) << 14) + (y << 7) + x;
    } else {
      int bn = rw >> 8, bb = bn >> 6, win = bn & 63, t = rw & 255;
      int y = (((win >> 3) << 4) + (t >> 4) + 8) & 127;
      int x = (((win & 7) << 4) + (t & 15) + 8) & 127;
      src = (bb << 14) + (y << 7) + x;
    }
    f4 a = *(const f4*)(A + (size_t)src * Dm + c4);
    s16x4 hv, lv;
    #pragma unroll
    for (int i = 0; i < 4; ++i) {
      u16 h = f2bf(a[i]);
      hv[i] = (short)h;
      lv[i] = (short)f2bf(a[i] - bf2f(h));
    }
    int word = r * 64 + ((c4 >> 1) ^ ((r & 7) << 2));
    *(s16x4*)&Ah[word * 2] = hv;
    *(s16x4*)&Al[word * 2] = lv;
  }
  __syncthreads();

  const int awb = (w * 16 + (l & 15)) * 64;
  const int swz = (l & 7) << 2;
  const int kg4 = (l >> 4) * 4;

  #pragma unroll
  for (int m = 0; m < NMAT; ++m) {
    const u16* bhp = (m == 0) ? wh0 : ((m == 1) ? wh1 : wh2);
    const u16* blp = (m == 0) ? wl0 : ((m == 1) ? wl1 : wl2);
    f32x4 acc[8];
    #pragma unroll
    for (int i = 0; i < 8; ++i) acc[i] = (f32x4)(0.f);
    #pragma unroll
    for (int ks = 0; ks < 4; ++ks) {
      int word = awb + ((ks * 16 + kg4) ^ swz);
      s16x8 ah = *(const s16x8*)&Ah[word * 2];
      s16x8 al = *(const s16x8*)&Al[word * 2];
      #pragma unroll
      for (int ct = 0; ct < 8; ++ct) {
        size_t fo = (size_t)(((ct * 4 + ks) * 64) + l) * 8;
        s16x8 bh = *(const s16x8*)(bhp + fo);
        s16x8 bl = *(const s16x8*)(blp + fo);
        acc[ct] = __builtin_amdgcn_mfma_f32_16x16x32_bf16(ah, bh, acc[ct], 0, 0, 0);
        acc[ct] = __builtin_amdgcn_mfma_f32_16x16x32_bf16(ah, bl, acc[ct], 0, 0, 0);
        acc[ct] = __builtin_amdgcn_mfma_f32_16x16x32_bf16(al, bh, acc[ct], 0, 0, 0);
      }
    }
    __syncthreads();   // protect ob from previous m's readers
    #pragma unroll
    for (int ct = 0; ct < 8; ++ct)
      #pragma unroll
      for (int j = 0; j < 4; ++j)
        ob[(w * 16 + (l >> 4) * 4 + j) * 132 + ct * 16 + (l & 15)] = acc[ct][j];
    __syncthreads();

    const bool isVt = (MODE == 0 && m == 2) || (MODE == 2 && m == 1);
    if (!isVt) {
      u16* oh = (m == 0) ? q_h : k_h;
      u16* ol = (m == 0) ? q_l : k_l;
      #pragma unroll
      for (int it = 0; it < 4; ++it) {
        int task = tid + it * 256;
        int r = task >> 4, h0 = (task & 15) * 8;
        f4 x0 = *(const f4*)&ob[r * 132 + h0];
        f4 x1 = *(const f4*)&ob[r * 132 + h0 + 4];
        s16x8 hv, lv;
        #pragma unroll
        for (int i = 0; i < 4; ++i) {
          u16 h = f2bf(x0[i]); hv[i] = (short)h; lv[i] = (short)f2bf(x0[i] - bf2f(h));
          u16 h2 = f2bf(x1[i]); hv[4 + i] = (short)h2; lv[4 + i] = (short)f2bf(x1[i] - bf2f(h2));
        }
        *(s16x8*)(oh + (size_t)(row0 + r) * Dm + h0) = hv;
        *(s16x8*)(ol + (size_t)(row0 + r) * Dm + h0) = lv;
      }
    } else {
      const int bn = row0 >> ((MODE == 2) ? 9 : 8);
      const int kk0 = row0 & (KC - 1);
      #pragma unroll
      for (int it = 0; it < 4; ++it) {
        int task = tid + it * 256;
        int d = task >> 3, k0 = (task & 7) * 8;
        s16x8 hv, lv;
        #pragma unroll
        for (int i = 0; i < 8; ++i) {
          float vv = ob[(k0 + i) * 132 + d];
          u16 h = f2bf(vv); hv[i] = (short)h; lv[i] = (short)f2bf(vv - bf2f(h));
        }
        size_t off = ((size_t)bn * 128 + d) * KC + kk0 + k0;
        *(s16x8*)(v_h + off) = hv;
        *(s16x8*)(v_l + off) = lv;
      }
    }
  }
}

// ---------------------------------------------------------------------------
// merge + LayerNorm (MFMA): Out = [resid +] LN(X @ W). Token-order rows.
// ---------------------------------------------------------------------------
template<bool ADD>
__global__ __launch_bounds__(256, 2)
void merge_mfma(const float* __restrict__ Xin,
                const u16* __restrict__ wh, const u16* __restrict__ wl,
                const float* __restrict__ g, const float* __restrict__ bi,
                const float* __restrict__ resid, float* __restrict__ Out)
{
  __shared__ __align__(16) u16 Ah[64 * 128];
  __shared__ __align__(16) u16 Al[64 * 128];
  __shared__ __align__(16) float ob[64 * 132];
  __shared__ float mus[64], rsts[64];
  const int tid = threadIdx.x;
  const int l = tid & 63, w = tid >> 6;
  const int row0 = blockIdx.x * 64;

  #pragma unroll
  for (int it = 0; it < 8; ++it) {
    int task = tid + it * 256;
    int r = task >> 5, c4 = (task & 31) * 4;
    f4 a = *(const f4*)(Xin + (size_t)(row0 + r) * Dm + c4);
    s16x4 hv, lv;
    #pragma unroll
    for (int i = 0; i < 4; ++i) {
      u16 h = f2bf(a[i]);
      hv[i] = (short)h;
      lv[i] = (short)f2bf(a[i] - bf2f(h));
    }
    int word = r * 64 + ((c4 >> 1) ^ ((r & 7) << 2));
    *(s16x4*)&Ah[word * 2] = hv;
    *(s16x4*)&Al[word * 2] = lv;
  }
  __syncthreads();

  const int awb = (w * 16 + (l & 15)) * 64;
  const int swz = (l & 7) << 2;
  const int kg4 = (l >> 4) * 4;

  f32x4 acc[8];
  #pragma unroll
  for (int i = 0; i < 8; ++i) acc[i] = (f32x4)(0.f);
  #pragma unroll
  for (int ks = 0; ks < 4; ++ks) {
    int word = awb + ((ks * 16 + kg4) ^ swz);
    s16x8 ah = *(const s16x8*)&Ah[word * 2];
    s16x8 al = *(const s16x8*)&Al[word * 2];
    #pragma unroll
    for (int ct = 0; ct < 8; ++ct) {
      size_t fo = (size_t)(((ct * 4 + ks) * 64) + l) * 8;
      s16x8 bh = *(const s16x8*)(wh + fo);
      s16x8 bl = *(const s16x8*)(wl + fo);
      acc[ct] = __builtin_amdgcn_mfma_f32_16x16x32_bf16(ah, bh, acc[ct], 0, 0, 0);
      acc[ct] = __builtin_amdgcn_mfma_f32_16x16x32_bf16(ah, bl, acc[ct], 0, 0, 0);
      acc[ct] = __builtin_amdgcn_mfma_f32_16x16x32_bf16(al, bh, acc[ct], 0, 0, 0);
    }
  }

  // row stats in D-layout
  float s[4] = {0.f, 0.f, 0.f, 0.f}, qq[4] = {0.f, 0.f, 0.f, 0.f};
  #pragma unroll
  for (int ct = 0; ct < 8; ++ct)
    #pragma unroll
    for (int j = 0; j < 4; ++j) {
      float v = acc[ct][j];
      s[j] += v; qq[j] += v * v;
    }
  #pragma unroll
  for (int j = 0; j < 4; ++j) {
    s[j] += __shfl_xor(s[j], 1); s[j] += __shfl_xor(s[j], 2);
    s[j] += __shfl_xor(s[j], 4); s[j] += __shfl_xor(s[j], 8);
    qq[j] += __shfl_xor(qq[j], 1); qq[j] += __shfl_xor(qq[j], 2);
    qq[j] += __shfl_xor(qq[j], 4); qq[j] += __shfl_xor(qq[j], 8);
  }
  if ((l & 15) == 0) {
    #pragma unroll
    for (int j = 0; j < 4; ++j) {
      int r = w * 16 + (l >> 4) * 4 + j;
      float mu = s[j] * (1.0f / 128.0f);
      float var = qq[j] * (1.0f / 128.0f) - mu * mu;
      mus[r] = mu;
      rsts[r] = 1.0f / sqrtf(var + 1e-5f);
    }
  }
  #pragma unroll
  for (int ct = 0; ct < 8; ++ct)
    #pragma unroll
    for (int j = 0; j < 4; ++j)
      ob[(w * 16 + (l >> 4) * 4 + j) * 132 + ct * 16 + (l & 15)] = acc[ct][j];
  __syncthreads();

  #pragma unroll
  for (int it = 0; it < 8; ++it) {
    int task = tid + it * 256;
    int r = task >> 5, c4 = (task & 31) * 4;
    f4 v = *(const f4*)&ob[r * 132 + c4];
    float mu = mus[r], rs = rsts[r];
    f4 g4 = *(const f4*)(g + c4);
    f4 b4 = *(const f4*)(bi + c4);
    f4 o = (v - mu) * rs * g4 + b4;
    if (ADD) o += *(const f4*)(resid + (size_t)(row0 + r) * Dm + c4);
    *(f4*)(Out + (size_t)(row0 + r) * Dm + c4) = o;
  }
}

// ---------------------------------------------------------------------------
// Flash-style windowed attention (MFMA, split-bf16).
// One block per window (512 thr, 8 waves, 32 q/wave). 64-key chunks.
// Q/K planes [row][128] bf16 hi/lo; V as V^T planes [bn][128][KC].
// Output X in token layout (inverse roll applied), fp32.
// ---------------------------------------------------------------------------
template<int MM>
__global__ __launch_bounds__(512, 2)
void attn_mfma(const u16* __restrict__ Qh, const u16* __restrict__ Ql,
               const u16* __restrict__ Kh, const u16* __restrict__ Kl,
               const u16* __restrict__ Vth, const u16* __restrict__ Vtl,
               float* __restrict__ X)
{
  constexpr int KC = 256 * MM;
  constexpr int NCH = KC / 64;
  __shared__ __align__(16) u16 lds[65536];   // 128 KB
  u16* Khs = lds;                 // [64][128] swizzled
  u16* Kls = lds + 8192;
  u16* Vhs = lds + 16384;         // [128][64] swizzled
  u16* Vls = lds + 24576;
  const int tid = threadIdx.x, l = tid & 63, w = tid >> 6;
  u16* Phs = lds + 32768 + w * 2048;   // wave-private [32][64] swizzled
  u16* Pls = lds + 49152 + w * 2048;

  const int bn = blockIdx.x, b = bn >> 6, win = bn & 63;
  const int wy = win >> 3, wx = win & 7;

  // Q fragments (resident)
  s16x8 qfh[2][4], qfl[2][4];
  #pragma unroll
  for (int qt = 0; qt < 2; ++qt)
    #pragma unroll
    for (int ks = 0; ks < 4; ++ks) {
      size_t off = ((size_t)bn * WSZ + w * 32 + qt * 16 + (l & 15)) * Dm
                 + ks * 32 + (l >> 4) * 8;
      qfh[qt][ks] = *(const s16x8*)(Qh + off);
      qfl[qt][ks] = *(const s16x8*)(Ql + off);
    }

  // region id of token index t within the (possibly edge) window
  auto region = [&](int t) -> int {
    int rh = (wy == 7) ? (((t >> 4) >= 8) ? 2 : 1) : 0;
    int rw_ = (wx == 7) ? (((t & 15) >= 8) ? 2 : 1) : 0;
    return rh * 3 + rw_;
  };
  int rq[2][4];
  #pragma unroll
  for (int qt = 0; qt < 2; ++qt)
    #pragma unroll
    for (int j = 0; j < 4; ++j)
      rq[qt][j] = region(w * 32 + qt * 16 + (l >> 4) * 4 + j);

  f32x4 o[2][8];
  #pragma unroll
  for (int qt = 0; qt < 2; ++qt)
    #pragma unroll
    for (int dt = 0; dt < 8; ++dt) o[qt][dt] = (f32x4)(0.f);
  float mrow[2][4], lrow[2][4];
  #pragma unroll
  for (int qt = 0; qt < 2; ++qt)
    #pragma unroll
    for (int j = 0; j < 4; ++j) { mrow[qt][j] = -1e30f; lrow[qt][j] = 0.f; }

  const int swz2 = (l & 7) << 2;
  const int swz3 = (l & 7) << 3;

  for (int ch = 0; ch < NCH; ++ch) {
    __syncthreads();
    // stage K chunk [64 keys][128 d] hi/lo, swizzled
    #pragma unroll
    for (int it = 0; it < 2; ++it) {
      int task = tid + it * 512;
      int r = task >> 4, hc = (task & 15) * 8;
      size_t src = ((size_t)bn * KC + ch * 64 + r) * Dm + hc;
      int word = r * 64 + ((hc >> 1) ^ ((r & 7) << 2));
      *(s16x8*)&Khs[word * 2] = *(const s16x8*)(Kh + src);
      *(s16x8*)&Kls[word * 2] = *(const s16x8*)(Kl + src);
    }
    // stage V^T chunk [128 d][64 keys] hi/lo, swizzled
    #pragma unroll
    for (int it = 0; it < 2; ++it) {
      int task = tid + it * 512;
      int d = task >> 3, hc = (task & 7) * 8;
      size_t src = ((size_t)bn * 128 + d) * KC + ch * 64 + hc;
      int word = d * 32 + ((hc >> 1) ^ ((d & 7) << 2));
      *(s16x8*)&Vhs[word * 2] = *(const s16x8*)(Vth + src);
      *(s16x8*)&Vls[word * 2] = *(const s16x8*)(Vtl + src);
    }
    __syncthreads();

    // QK^T + online softmax, per q-tile
    #pragma unroll
    for (int qt = 0; qt < 2; ++qt) {
      float pb[4][4];
      #pragma unroll
      for (int kt = 0; kt < 4; ++kt) {
        f32x4 sc = (f32x4)(0.f);
        #pragma unroll
        for (int ks = 0; ks < 4; ++ks) {
          int word = (kt * 16 + (l & 15)) * 64 + ((ks * 16 + (l >> 4) * 4) ^ swz2);
          s16x8 bh = *(const s16x8*)&Khs[word * 2];
          s16x8 bl = *(const s16x8*)&Kls[word * 2];
          sc = __builtin_amdgcn_mfma_f32_16x16x32_bf16(qfh[qt][ks], bh, sc, 0, 0, 0);
          sc = __builtin_amdgcn_mfma_f32_16x16x32_bf16(qfh[qt][ks], bl, sc, 0, 0, 0);
          sc = __builtin_amdgcn_mfma_f32_16x16x32_bf16(qfl[qt][ks], bh, sc, 0, 0, 0);
        }
        int kk = ch * 64 + kt * 16 + (l & 15);
        int rk = region(kk & 255);
        #pragma unroll
        for (int j = 0; j < 4; ++j)
          pb[kt][j] = sc[j] * SCALE + ((rq[qt][j] == rk) ? 0.f : -100.f);
      }
      #pragma unroll
      for (int j = 0; j < 4; ++j) {
        float pm = fmaxf(fmaxf(pb[0][j], pb[1][j]), fmaxf(pb[2][j], pb[3][j]));
        pm = fmaxf(pm, __shfl_xor(pm, 1));
        pm = fmaxf(pm, __shfl_xor(pm, 2));
        pm = fmaxf(pm, __shfl_xor(pm, 4));
        pm = fmaxf(pm, __shfl_xor(pm, 8));
        float mold = mrow[qt][j];
        float mnew = fmaxf(mold, pm);
        float f = __expf(mold - mnew);
        mrow[qt][j] = mnew;
        lrow[qt][j] *= f;
        #pragma unroll
        for (int dt = 0; dt < 8; ++dt) o[qt][dt][j] *= f;
        int qloc = qt * 16 + (l >> 4) * 4 + j;
        int sw = (qloc & 7) << 3;
        #pragma unroll
        for (int kt = 0; kt < 4; ++kt) {
          float p = __expf(pb[kt][j] - mnew);
          lrow[qt][j] += p;
          u16 ph = f2bf(p);
          u16 pl = f2bf(p - bf2f(ph));
          int key = kt * 16 + (l & 15);
          int hidx = qloc * 64 + (key ^ sw);
          Phs[hidx] = ph;
          Pls[hidx] = pl;
        }
      }
    }

    // PV: O += P (A) x V (B)
    #pragma unroll
    for (int qt = 0; qt < 2; ++qt)
      #pragma unroll
      for (int ks2 = 0; ks2 < 2; ++ks2) {
        int hidxA = (qt * 16 + (l & 15)) * 64 + ((ks2 * 32 + (l >> 4) * 8) ^ swz3);
        s16x8 ah = *(const s16x8*)&Phs[hidxA];
        s16x8 al = *(const s16x8*)&Pls[hidxA];
        #pragma unroll
        for (int dt = 0; dt < 8; ++dt) {
          int word = (dt * 16 + (l & 15)) * 32 + ((ks2 * 16 + (l >> 4) * 4) ^ swz2);
          s16x8 bh = *(const s16x8*)&Vhs[word * 2];
          s16x8 bl = *(const s16x8*)&Vls[word * 2];
          o[qt][dt] = __builtin_amdgcn_mfma_f32_16x16x32_bf16(ah, bh, o[qt][dt], 0, 0, 0);
          o[qt][dt] = __builtin_amdgcn_mfma_f32_16x16x32_bf16(ah, bl, o[qt][dt], 0, 0, 0);
          o[qt][dt] = __builtin_amdgcn_mfma_f32_16x16x32_bf16(al, bh, o[qt][dt], 0, 0, 0);
        }
      }
  }

  // finalize: divide by row sums, write X (token layout)
  float linv[2][4];
  #pragma unroll
  for (int qt = 0; qt < 2; ++qt)
    #pragma unroll
    for (int j = 0; j < 4; ++j) {
      float sv = lrow[qt][j];
      sv += __shfl_xor(sv, 1); sv += __shfl_xor(sv, 2);
      sv += __shfl_xor(sv, 4); sv += __shfl_xor(sv, 8);
      linv[qt][j] = 1.0f / sv;
    }
  __syncthreads();
  float* ob = (float*)lds;   // [256][128] fp32 = 128 KB
  #pragma unroll
  for (int qt = 0; qt < 2; ++qt)
    #pragma unroll
    for (int dt = 0; dt < 8; ++dt)
      #pragma unroll
      for (int j = 0; j < 4; ++j)
        ob[(w * 32 + qt * 16 + (l >> 4) * 4 + j) * 128 + dt * 16 + (l & 15)] =
            o[qt][dt][j] * linv[qt][j];
  __syncthreads();
  #pragma unroll
  for (int it = 0; it < 16; ++it) {
    int task = tid + it * 512;
    int r = task >> 5, c4 = (task & 31) * 4;
    int y = ((wy << 4) + (r >> 4) + 8) & 127;
    int x = ((wx << 4) + (r & 15) + 8) & 127;
    *(f4*)(X + ((size_t)(b << 14) + (y << 7) + x) * Dm + c4) = *(const f4*)&ob[r * 128 + c4];
  }
}

// ---------------------------------------------------------------------------
// Fused MLP (round-1 verified): out = SRC + LN(gelu(concat(SRC,MSG)@W1)@W2)
// ---------------------------------------------------------------------------
__global__ __launch_bounds__(512)
void mlp_mfma_kernel(const float* __restrict__ SRC, const float* __restrict__ MSG,
                     const u16* __restrict__ w1h, const u16* __restrict__ w1l,
                     const u16* __restrict__ w2h, const u16* __restrict__ w2l,
                     const float* __restrict__ g, const float* __restrict__ bi,
                     float* __restrict__ Out)
{
  __shared__ __align__(16) u16 Xh[64 * 256];
  __shared__ __align__(16) u16 Xl[64 * 256];
  __shared__ __align__(16) u16 Hh[64 * 128];
  __shared__ __align__(16) u16 Hl[64 * 128];

  const int tid  = threadIdx.x;
  const int row0 = blockIdx.x * 64;
  const int l    = tid & 63;
  const int w    = tid >> 6;
  const int rt   = w & 3;
  const int ctg  = w >> 2;

  #pragma unroll
  for (int s = 0; s < 8; ++s) {
    int slot = tid + s * 512;
    int row  = slot >> 6;
    int c4   = (slot & 63) * 4;
    const float* p = (c4 < 128) ? (SRC + (size_t)(row0 + row) * Dm + c4)
                                : (MSG + (size_t)(row0 + row) * Dm + (c4 - 128));
    f4 a = *(const f4*)p;
    s16x4 hv, lv;
    #pragma unroll
    for (int i = 0; i < 4; ++i) {
      u16 h = f2bf(a[i]);
      hv[i] = (short)h;
      lv[i] = (short)f2bf(a[i] - bf2f(h));
    }
    int word = row * 128 + ((c4 >> 1) ^ ((row & 7) << 2));
    *(s16x4*)&Xh[word * 2] = hv;
    *(s16x4*)&Xl[word * 2] = lv;
  }

  f32x4 acc[4];
  #pragma unroll
  for (int i = 0; i < 4; ++i) acc[i] = (f32x4)(0.f);

  const int swz  = (l & 7) << 2;
  const int arow = rt * 16 + (l & 15);
  const int kgrp = (l >> 4) * 8;

  __syncthreads();

  for (int c = 0; c < 8; ++c) {
    f32x4 acc1[4];
    #pragma unroll
    for (int i = 0; i < 4; ++i) acc1[i] = (f32x4)(0.f);
    #pragma unroll 2
    for (int ks = 0; ks < 8; ++ks) {
      int k0 = ks * 32 + kgrp;
      int word = arow * 128 + ((k0 >> 1) ^ swz);
      s16x8 ah = *(const s16x8*)&Xh[word * 2];
      s16x8 al = *(const s16x8*)&Xl[word * 2];
      #pragma unroll
      for (int t = 0; t < 4; ++t) {
        int ct = ctg * 4 + t;
        size_t fo = (size_t)(((c * 8 + ct) * 8 + ks) * 64 + l) * 8;
        s16x8 bh = *(const s16x8*)(w1h + fo);
        s16x8 bl = *(const s16x8*)(w1l + fo);
        acc1[t] = __builtin_amdgcn_mfma_f32_16x16x32_bf16(ah, bh, acc1[t], 0, 0, 0);
        acc1[t] = __builtin_amdgcn_mfma_f32_16x16x32_bf16(ah, bl, acc1[t], 0, 0, 0);
        acc1[t] = __builtin_amdgcn_mfma_f32_16x16x32_bf16(al, bh, acc1[t], 0, 0, 0);
      }
    }
    __syncthreads();
    #pragma unroll
    for (int t = 0; t < 4; ++t) {
      int col = (ctg * 4 + t) * 16 + (l & 15);
      #pragma unroll
      for (int j = 0; j < 4; ++j) {
        int row = rt * 16 + (l >> 4) * 4 + j;
        float x = acc1[t][j];
        float ge = 0.5f * x * (1.0f + erff(x * 0.70710678118654752f));
        u16 h  = f2bf(ge);
        u16 lo = f2bf(ge - bf2f(h));
        int word = row * 64 + ((col >> 1) ^ ((row & 7) << 2));
        int idx = word * 2 + (col & 1);
        Hh[idx] = h;
        Hl[idx] = lo;
      }
    }
    __syncthreads();
    #pragma unroll
    for (int ks = 0; ks < 4; ++ks) {
      int k0 = ks * 32 + kgrp;
      int word = arow * 64 + ((k0 >> 1) ^ swz);
      s16x8 ah = *(const s16x8*)&Hh[word * 2];
      s16x8 al = *(const s16x8*)&Hl[word * 2];
      #pragma unroll
      for (int t = 0; t < 4; ++t) {
        int ct = ctg * 4 + t;
        size_t fo = (size_t)(((c * 4 + ks) * 8 + ct) * 64 + l) * 8;
        s16x8 bh = *(const s16x8*)(w2h + fo);
        s16x8 bl = *(const s16x8*)(w2l + fo);
        acc[t] = __builtin_amdgcn_mfma_f32_16x16x32_bf16(ah, bh, acc[t], 0, 0, 0);
        acc[t] = __builtin_amdgcn_mfma_f32_16x16x32_bf16(ah, bl, acc[t], 0, 0, 0);
        acc[t] = __builtin_amdgcn_mfma_f32_16x16x32_bf16(al, bh, acc[t], 0, 0, 0);
      }
    }
  }

  __syncthreads();
  float* ob = (float*)Xh;
  #pragma unroll
  for (int t = 0; t < 4; ++t) {
    int col = (ctg * 4 + t) * 16 + (l & 15);
    #pragma unroll
    for (int j = 0; j < 4; ++j) {
      int row = rt * 16 + (l >> 4) * 4 + j;
      ob[row * 128 + col] = acc[t][j];
    }
  }
  __syncthreads();
  {
    int row = tid >> 3, sub = tid & 7;
    const float* rp = ob + row * 128;
    f4 v[4];
    #pragma unroll
    for (int s = 0; s < 4; ++s) v[s] = *(const f4*)(rp + sub * 4 + s * 32);
    float sm = 0.f;
    #pragma unroll
    for (int s = 0; s < 4; ++s) sm += v[s][0] + v[s][1] + v[s][2] + v[s][3];
    sm += __shfl_xor(sm, 1); sm += __shfl_xor(sm, 2); sm += __shfl_xor(sm, 4);
    float mu = sm * (1.0f / 128.0f);
    float qs = 0.f;
    #pragma unroll
    for (int s = 0; s < 4; ++s) {
      v[s] -= mu;
      qs += v[s][0] * v[s][0] + v[s][1] * v[s][1] + v[s][2] * v[s][2] + v[s][3] * v[s][3];
    }
    qs += __shfl_xor(qs, 1); qs += __shfl_xor(qs, 2); qs += __shfl_xor(qs, 4);
    float rstd = 1.0f / sqrtf(qs * (1.0f / 128.0f) + 1e-5f);
    #pragma unroll
    for (int s = 0; s < 4; ++s) {
      int cc = sub * 4 + s * 32;
      f4 g4 = *(const f4*)(g + cc);
      f4 b4 = *(const f4*)(bi + cc);
      f4 rv = *(const f4*)(SRC + (size_t)(row0 + row) * Dm + cc);
      f4 o = v[s] * rstd * g4 + b4 + rv;
      *(f4*)(Out + (size_t)(row0 + row) * Dm + cc) = o;
    }
  }
}

// ---------------------------------------------------------------------------
extern "C" void kernel_launch(void* const* d_in, const int* in_sizes, int n_in,
                              void* d_out, int out_size, void* d_ws, size_t ws_size,
                              hipStream_t stream)
{
  const float* source = (const float*)d_in[0];
  const float* kv     = (const float*)d_in[1];
  const float* q1    = (const float*)d_in[3];
  const float* k1    = (const float*)d_in[4];
  const float* v1    = (const float*)d_in[5];
  const float* m1    = (const float*)d_in[6];
  const float* ln1g  = (const float*)d_in[7];
  const float* ln1b  = (const float*)d_in[8];
  const float* q2    = (const float*)d_in[9];
  const float* k2    = (const float*)d_in[10];
  const float* v2    = (const float*)d_in[11];
  const float* m2    = (const float*)d_in[12];
  const float* ln2ag = (const float*)d_in[13];
  const float* ln2ab = (const float*)d_in[14];
  const float* w1    = (const float*)d_in[15];
  const float* w2    = (const float*)d_in[16];
  const float* ln2bg = (const float*)d_in[17];
  const float* ln2bb = (const float*)d_in[18];

  char* base = (char*)d_ws;
  char* Ab = base;                       // 50,331,648 B
  char* Bb = base + 50331648;            // 100,663,296 B
  char* Cb = Bb + 100663296;             // 100,663,296 B
  char* Db = Cb + 100663296;             // 50,331,648 B

  u16* Qh = (u16*)Ab;
  u16* Ql = (u16*)(Ab + 25165824);
  float* MSG2 = (float*)Ab;
  u16* Kh = (u16*)Bb;
  u16* Kl_s = (u16*)(Bb + 25165824);     // self K lo plane
  u16* Kl_c = (u16*)(Bb + 50331648);     // cross K lo plane
  u16* Vth = (u16*)Cb;
  u16* Vtl_s = (u16*)(Cb + 25165824);
  u16* Vtl_c = (u16*)(Cb + 50331648);
  float* X = (float*)Db;
  float* SRCb = (float*)d_out;

  // transient weight-frag regions
  u16* fragD  = (u16*)Db;                // q1/k1/v1, later k2/v2
  u16* fragB2 = (u16*)(Bb + 50331648);   // m1, q2 (free until cross-K write)
  u16* w1h = (u16*)Bb;                   // after attn2: W1/W2/m2 frags
  u16* w1l = w1h + 262144;
  u16* w2h = w1l + 262144;
  u16* w2l = w2h + 131072;
  u16* m2h = w2l + 131072;
  u16* m2l = m2h + 16384;

  // 1. prep q1,k1,v1 frags -> D
  prep_dxd<<<192, 256, 0, stream>>>(q1, k1, v1, fragD);
  // 2. prep m1,q2 frags -> B second half
  prep_dxd<<<128, 256, 0, stream>>>(m1, q2, q2, fragB2);
  // 3. self qkv projection -> Q/K planes + self V^T
  proj_mfma<0, 3, 256><<<1536, 256, 0, stream>>>(
      source, fragD, fragD + 16384, fragD + 32768, fragD + 49152,
      fragD + 65536, fragD + 81920,
      Qh, Ql, Kh, Kl_s, Vth, Vtl_s);
  // 4. self window attention -> X
  attn_mfma<1><<<384, 512, 0, stream>>>(Qh, Ql, Kh, Kl_s, Vth, Vtl_s, X);
  // 5. src = source + LN(X @ m1) -> d_out
  merge_mfma<true><<<1536, 256, 0, stream>>>(X, fragB2, fragB2 + 16384,
                                             ln1g, ln1b, source, SRCb);
  // 6. prep k2,v2 frags -> D (X dead)
  prep_dxd<<<128, 256, 0, stream>>>(k2, v2, v2, fragD);
  // 7. q2 projection -> Q planes
  proj_mfma<1, 1, 256><<<1536, 256, 0, stream>>>(
      SRCb, fragB2 + 32768, fragB2 + 49152, nullptr, nullptr, nullptr, nullptr,
      Qh, Ql, nullptr, nullptr, nullptr, nullptr);
  // 8. cross kv projection -> K planes (full B) + cross V^T
  proj_mfma<2, 2, 512><<<3072, 256, 0, stream>>>(
      kv, fragD, fragD + 16384, fragD + 32768, fragD + 49152, nullptr, nullptr,
      Kh, Kl_c, nullptr, nullptr, Vth, Vtl_c);
  // 9. cross window attention -> X
  attn_mfma<2><<<384, 512, 0, stream>>>(Qh, Ql, Kh, Kl_c, Vth, Vtl_c, X);
  // 10. prep W1/W2/m2 frags -> B (K dead)
  prep_w1w2m2<<<1600, 256, 0, stream>>>(w1, w2, m2, w1h, w1l, w2h, w2l, m2h, m2l);
  // 11. msg2 = LN(X @ m2) -> MSG2 (A region; Q planes dead)
  merge_mfma<false><<<1536, 256, 0, stream>>>(X, m2h, m2l, ln2ag, ln2ab,
                                              nullptr, MSG2);
  // 12. fused MLP + LN + residual -> d_out
  mlp_mfma_kernel<<<1536, 512, 0, stream>>>(SRCb, MSG2, w1h, w1l, w2h, w2l,
                                            ln2bg, ln2bb, (float*)d_out);
}